// Round 11
// baseline (165.117 us; speedup 1.0000x reference)
//
#include <hip/hip_runtime.h>
#include <math.h>

#define NS 1024   // speakers
#define NU 64     // utterances per speaker
#define NE 256    // embedding dim

typedef __attribute__((ext_vector_type(8))) short short8;
typedef __attribute__((ext_vector_type(4))) float f32x4;
typedef __attribute__((ext_vector_type(4))) unsigned short us4;

// round-to-nearest-even fp32 -> bf16 bits
__device__ static inline unsigned short f2bf(float f) {
  unsigned int u = __float_as_uint(f);
  unsigned int r = (u + 0x7fffu + ((u >> 16) & 1u)) >> 16;
  return (unsigned short)r;
}

// ws layout (bytes):
//   Cb    @ 0     : 1024*256 bf16 (512 KB), MFMA-B-permuted
//   packG @ 512K  : 65536 u32 (256 KB)  (p_bits & ~1023) | (1023-col)
//   ssumG @ 768K  : 65536 f32 (256 KB)  sum of exp(l-M0) per row
//   gtlG  @ 1024K : 65536 f32 (256 KB)  ground-truth logit per row
//   normsum @1280K: 1024 f32
//
// Cb layout: global 1KB block G = (n>>4)*8 + (k>>5); within block,
//   idx(n,k) = G*512 + (((k>>3)&3)*16 + (n&15))*8 + (k&7)   (ushort units)
// As short8 fragments: frag(tile gt, kstep s, lane) = cb8[gt*512 + s*64 + lane]

__global__ __launch_bounds__(256) void centroid_kernel(
    const float* __restrict__ embeds, unsigned short* __restrict__ Cb,
    float* __restrict__ normsum, float* __restrict__ ssumG,
    unsigned int* __restrict__ packG, float* __restrict__ out) {
  int k = blockIdx.x;   // speaker
  int t = threadIdx.x;
  // zero the per-row accumulators (ws re-poisoned every launch)
  if (t < 64) {
    ssumG[k * 64 + t] = 0.f;
    packG[k * 64 + t] = 0u;
  }
  int wave = t >> 6, e4 = t & 63;
  const float4* base =
      (const float4*)(embeds + (size_t)k * NU * NE) + wave * 16 * 64 + e4;
  float4 s = {0.f, 0.f, 0.f, 0.f};
#pragma unroll
  for (int i = 0; i < 16; ++i) {
    float4 v = base[i * 64];
    s.x += v.x; s.y += v.y; s.z += v.z; s.w += v.w;
  }
  __shared__ float4 ps[4][64];
  ps[wave][e4] = s;
  __syncthreads();
  if (t < 64) {
    float4 a = ps[0][t], b = ps[1][t], c = ps[2][t], d = ps[3][t];
    float4 s4;
    s4.x = a.x + b.x + c.x + d.x;
    s4.y = a.y + b.y + c.y + d.y;
    s4.z = a.z + b.z + c.z + d.z;
    s4.w = a.w + b.w + c.w + d.w;
    float sq = s4.x * s4.x + s4.y * s4.y + s4.z * s4.z + s4.w * s4.w;
#pragma unroll
    for (int off = 32; off; off >>= 1) sq += __shfl_xor(sq, off, 64);
    float nrm = sqrtf(sq);
    float inv = 1.f / nrm;
    int G = (k >> 4) * 8 + (t >> 3);
    int off = (((t >> 1) & 3) * 16 + (k & 15)) * 8 + (t & 1) * 4;
    us4 v;
    v[0] = f2bf(s4.x * inv);
    v[1] = f2bf(s4.y * inv);
    v[2] = f2bf(s4.z * inv);
    v[3] = f2bf(s4.w * inv);
    *(us4*)(Cb + (size_t)G * 512 + off) = v;
    if (t == 0) {
      normsum[k] = nrm;
      if (k == 0) { out[0] = 0.f; out[1] = 0.f; }
    }
  }
}

// Barrier-free main: B-fragments read directly from L2 (Cb = 512 KB,
// L2-resident per XCD). No LDS, no __syncthreads — waves fully independent.
// B-frags pipelined in two 4-frag groups, loaded IN PLACE to cap liveness.
__global__ __launch_bounds__(256, 2) void main_kernel(
    const float* __restrict__ embeds, const unsigned short* __restrict__ Cb,
    const float* __restrict__ normsum, const float* __restrict__ wp,
    const float* __restrict__ bp, float* __restrict__ ssumG,
    unsigned int* __restrict__ packG, float* __restrict__ gtlG) {
  int t = threadIdx.x;
  int wave = t >> 6, lane = t & 63;
  int c = lane & 15, q = lane >> 4;
  int b = blockIdx.x;               // 0..1023
  int rg = b >> 1;                  // row group 0..511
  int h = b & 1;                    // column half: cols [h*512, h*512+512)
  int jspk = rg * 2 + (wave >> 1);  // this wave's speaker (diag column)
  int r0 = rg * 128 + wave * 32;    // global row base for this wave

  float w = *wp, bia = *bp;
  const float L2E = 1.4426950408889634f;
  float M0 = fabsf(w) + bia;        // >= any logit (cosines in [-1,1])
  float wl = w * L2E;               // p = 2^(d*wl + cl) = exp(l - M0)
  float cl = (bia - M0) * L2E;
  float ns = normsum[jspk];

  const short8* cb8 = (const short8*)Cb;
  int fb = h * 32 * 512 + lane;     // fragment index base for this half

  // ---- issue tile-0 B loads early (overlap with A-phase) ----
  short8 bfA[4], bfB[4];
#pragma unroll
  for (int s = 0; s < 4; ++s) bfA[s] = cb8[fb + s * 64];
#pragma unroll
  for (int s = 0; s < 4; ++s) bfB[s] = cb8[fb + (4 + s) * 64];

  // ---- A fragments (32 rows x 256 K per wave) + row norms ----
  // A-frag layout: lane holds A[m = lane&15][k = q*8 + j], per (mtile, kstep)
  short8 af[2][8];
  float n2p[2];
#pragma unroll
  for (int mt = 0; mt < 2; ++mt) {
    const float* rowp = embeds + (size_t)(r0 + mt * 16 + c) * NE;
    float acc2 = 0.f;
#pragma unroll
    for (int s = 0; s < 8; ++s) {
      int k0 = s * 32 + q * 8;
      float4 x = *(const float4*)(rowp + k0);
      float4 y = *(const float4*)(rowp + k0 + 4);
      acc2 += x.x * x.x + x.y * x.y + x.z * x.z + x.w * x.w;
      acc2 += y.x * y.x + y.y * y.y + y.z * y.z + y.w * y.w;
      short8 f;
      f[0] = (short)f2bf(x.x); f[1] = (short)f2bf(x.y);
      f[2] = (short)f2bf(x.z); f[3] = (short)f2bf(x.w);
      f[4] = (short)f2bf(y.x); f[5] = (short)f2bf(y.y);
      f[6] = (short)f2bf(y.z); f[7] = (short)f2bf(y.w);
      af[mt][s] = f;
    }
    n2p[mt] = acc2;
  }
#pragma unroll
  for (int mt = 0; mt < 2; ++mt) {
    n2p[mt] += __shfl_xor(n2p[mt], 16, 64);  // reduce across q-groups
    n2p[mt] += __shfl_xor(n2p[mt], 32, 64);
  }
  // n2 of the rows THIS lane's C-registers cover (rows q*4+r), via shuffle
  float n2d[2][4];
#pragma unroll
  for (int mt = 0; mt < 2; ++mt)
#pragma unroll
    for (int r = 0; r < 4; ++r)
      n2d[mt][r] = __shfl(n2p[mt], q * 4 + r, 64);

  // ---- per-lane softmax state ----
  float ssum[2][4];
  unsigned int pm[2][4];
#pragma unroll
  for (int mt = 0; mt < 2; ++mt)
#pragma unroll
    for (int r = 0; r < 4; ++r) {
      ssum[mt][r] = 0.f;
      pm[mt][r] = 0u;
    }

  // ---- barrier-free loop over this half's 32 column tiles ----
#pragma unroll 1
  for (int T = 0; T < 32; ++T) {
    f32x4 acc0 = {0.f, 0.f, 0.f, 0.f};
    f32x4 acc1 = {0.f, 0.f, 0.f, 0.f};
    int nb = fb + (T + 1) * 512;
    bool more = (T + 1 < 32);
    // first half of K with group A, then refill group A for tile T+1
#pragma unroll
    for (int s = 0; s < 4; ++s) {
      acc0 = __builtin_amdgcn_mfma_f32_16x16x32_bf16(af[0][s], bfA[s], acc0,
                                                     0, 0, 0);
      acc1 = __builtin_amdgcn_mfma_f32_16x16x32_bf16(af[1][s], bfA[s], acc1,
                                                     0, 0, 0);
    }
    if (more) {
#pragma unroll
      for (int s = 0; s < 4; ++s) bfA[s] = cb8[nb + s * 64];
    }
    // second half of K with group B, then refill group B for tile T+1
#pragma unroll
    for (int s = 0; s < 4; ++s) {
      acc0 = __builtin_amdgcn_mfma_f32_16x16x32_bf16(af[0][4 + s], bfB[s],
                                                     acc0, 0, 0, 0);
      acc1 = __builtin_amdgcn_mfma_f32_16x16x32_bf16(af[1][4 + s], bfB[s],
                                                     acc1, 0, 0, 0);
    }
    if (more) {
#pragma unroll
      for (int s = 0; s < 4; ++s) bfB[s] = cb8[nb + (4 + s) * 64];
    }

    int gt = h * 32 + T;
    int col = gt * 16 + c;
    bool diagstep = ((jspk >> 4) == gt);  // wave-uniform
#pragma unroll
    for (int mt = 0; mt < 2; ++mt) {
      f32x4 a = mt ? acc1 : acc0;
      if (diagstep && c == (jspk & 15)) {
#pragma unroll
        for (int r = 0; r < 4; ++r) {
          float d = a[r];
          float n2 = n2d[mt][r];
          float Sv = d * ns;
          float den = fmaxf(fmaf(ns, ns, n2) - 2.f * Sv, 1e-30f);
          float val = (Sv - n2) * __frsqrt_rn(den);
          gtlG[r0 + mt * 16 + q * 4 + r] = fmaf(w, val, bia);
          a[r] = val;
        }
      }
#pragma unroll
      for (int r = 0; r < 4; ++r) {
        float p = exp2f(fmaf(a[r], wl, cl));  // exp(l - M0), monotone in l
        ssum[mt][r] += p;
        // pack p (top 22 bits) with 1023-col: argmax with low-col ties
        unsigned int pk =
            (__float_as_uint(p) & 0xfffffc00u) | (unsigned)(1023 - col);
        pm[mt][r] = pm[mt][r] > pk ? pm[mt][r] : pk;
      }
    }
  }

  // ---- cross-lane (16 column-lanes) reduce, then global atomic combine ----
#pragma unroll
  for (int mt = 0; mt < 2; ++mt)
#pragma unroll
    for (int r = 0; r < 4; ++r) {
      float s = ssum[mt][r];
      s += __shfl_xor(s, 1, 64);
      s += __shfl_xor(s, 2, 64);
      s += __shfl_xor(s, 4, 64);
      s += __shfl_xor(s, 8, 64);
      unsigned int m = pm[mt][r];
#pragma unroll
      for (int off = 1; off < 16; off <<= 1) {
        unsigned int m2 = __shfl_xor((int)m, off, 64);
        m = m > m2 ? m : m2;
      }
      if (c == 0) {
        int row = r0 + mt * 16 + q * 4 + r;
        atomicAdd(&ssumG[row], s);
        atomicMax(&packG[row], m);
      }
    }
}

__global__ __launch_bounds__(256) void reduce_kernel(
    const float* __restrict__ ssumG, const unsigned int* __restrict__ packG,
    const float* __restrict__ gtlG, const float* __restrict__ wp,
    const float* __restrict__ bp, float* __restrict__ out) {
  int i = blockIdx.x * 256 + threadIdx.x;  // row 0..65535
  int spk = i >> 6;
  float w = *wp, bia = *bp;
  float M0 = fabsf(w) + bia;
  float lossr = M0 + __logf(ssumG[i]) - gtlG[i];
  int amax = 1023 - (int)(packG[i] & 1023u);
  float corr = (amax == spk) ? 1.f : 0.f;
#pragma unroll
  for (int off = 32; off; off >>= 1) {
    lossr += __shfl_xor(lossr, off, 64);
    corr += __shfl_xor(corr, off, 64);
  }
  __shared__ float pl[4], pc[4];
  int wave = threadIdx.x >> 6, lane = threadIdx.x & 63;
  if (lane == 0) { pl[wave] = lossr; pc[wave] = corr; }
  __syncthreads();
  if (threadIdx.x == 0) {
    const float inv = 1.f / (float)(NS * NU);
    atomicAdd(&out[0], (pl[0] + pl[1] + pl[2] + pl[3]) * inv);
    atomicAdd(&out[1], (pc[0] + pc[1] + pc[2] + pc[3]) * inv);
  }
}

extern "C" void kernel_launch(void* const* d_in, const int* in_sizes, int n_in,
                              void* d_out, int out_size, void* d_ws,
                              size_t ws_size, hipStream_t stream) {
  const float* embeds = (const float*)d_in[0];
  const float* w = (const float*)d_in[1];
  const float* b = (const float*)d_in[2];
  float* out = (float*)d_out;
  char* ws = (char*)d_ws;
  unsigned short* Cb = (unsigned short*)ws;              // 512 KB
  unsigned int* packG = (unsigned int*)(ws + (512 << 10));  // 256 KB
  float* ssumG = (float*)(ws + (768 << 10));             // 256 KB
  float* gtlG = (float*)(ws + (1024 << 10));             // 256 KB
  float* normsum = (float*)(ws + (1280 << 10));          // 4 KB

  centroid_kernel<<<NS, 256, 0, stream>>>(embeds, Cb, normsum, ssumG, packG,
                                          out);
  main_kernel<<<1024, 256, 0, stream>>>(embeds, Cb, normsum, w, b, ssumG,
                                        packG, gtlG);
  reduce_kernel<<<NS * NU / 256, 256, 0, stream>>>(ssumG, packG, gtlG, w, b,
                                                   out);
}

// Round 12
// 159.282 us; speedup vs baseline: 1.0366x; 1.0366x over previous
//
#include <hip/hip_runtime.h>
#include <math.h>

#define NS 1024   // speakers
#define NU 64     // utterances per speaker
#define NE 256    // embedding dim

typedef __attribute__((ext_vector_type(4))) float f32x4;

// pack 4 floats -> 4 fp8 e4m3 bytes (HW cvt, OCP on gfx950)
__device__ static inline unsigned int pk4_fp8(float a, float b, float c,
                                              float d) {
  int r = 0;
  r = __builtin_amdgcn_cvt_pk_fp8_f32(a, b, r, false);  // bytes 0,1
  r = __builtin_amdgcn_cvt_pk_fp8_f32(c, d, r, true);   // bytes 2,3
  return (unsigned int)r;
}

// ws layout (bytes):
//   Cb    @ 0     : 1024 cols x 256 k fp8 (256 KB), MFMA-B-fragment-permuted
//   packG @ 256K  : 65536 u32 (256 KB)  (p_bits & ~1023) | (1023-col)
//   ssumG @ 512K  : 65536 f32 (256 KB)  sum of exp(l-M0) per row
//   gtlG  @ 768K  : 65536 f32 (256 KB)  ground-truth logit per row
//   normsum @1024K: 1024 f32
//
// Cb layout (fp8): for column n, element k:
//   tile gt = n>>4 (4096 B each), step s = k>>5 (512 B each),
//   lane = ((k>>3)&3)*16 + (n&15) (8 B each), byte j = k&7.
// As u64 fragments: frag(gt, s, lane) = cb[gt*512 + s*64 + lane]

__global__ __launch_bounds__(256) void centroid_kernel(
    const float* __restrict__ embeds, unsigned int* __restrict__ Cb,
    float* __restrict__ normsum, float* __restrict__ ssumG,
    unsigned int* __restrict__ packG, float* __restrict__ out) {
  int k = blockIdx.x;   // speaker
  int t = threadIdx.x;
  // zero the per-row accumulators (ws re-poisoned every launch)
  if (t < 64) {
    ssumG[k * 64 + t] = 0.f;
    packG[k * 64 + t] = 0u;
  }
  int wave = t >> 6, e4 = t & 63;
  const float4* base =
      (const float4*)(embeds + (size_t)k * NU * NE) + wave * 16 * 64 + e4;
  float4 s = {0.f, 0.f, 0.f, 0.f};
#pragma unroll
  for (int i = 0; i < 16; ++i) {
    float4 v = base[i * 64];
    s.x += v.x; s.y += v.y; s.z += v.z; s.w += v.w;
  }
  __shared__ float4 ps[4][64];
  ps[wave][e4] = s;
  __syncthreads();
  if (t < 64) {
    float4 a = ps[0][t], b = ps[1][t], c = ps[2][t], d = ps[3][t];
    float4 s4;
    s4.x = a.x + b.x + c.x + d.x;
    s4.y = a.y + b.y + c.y + d.y;
    s4.z = a.z + b.z + c.z + d.z;
    s4.w = a.w + b.w + c.w + d.w;
    float sq = s4.x * s4.x + s4.y * s4.y + s4.z * s4.z + s4.w * s4.w;
#pragma unroll
    for (int off = 32; off; off >>= 1) sq += __shfl_xor(sq, off, 64);
    float nrm = sqrtf(sq);
    float inv = 1.f / nrm;
    // elements e = 4t..4t+3 -> uint index:
    // (k>>4)*1024 + (t>>3)*128 + (((t>>1)&3)*16 + (k&15))*2 + (t&1)
    unsigned int v = pk4_fp8(s4.x * inv, s4.y * inv, s4.z * inv, s4.w * inv);
    int idx = (k >> 4) * 1024 + (t >> 3) * 128 +
              ((((t >> 1) & 3) * 16 + (k & 15)) << 1) + (t & 1);
    Cb[idx] = v;
    if (t == 0) {
      normsum[k] = nrm;
      if (k == 0) { out[0] = 0.f; out[1] = 0.f; }
    }
  }
}

// Barrier-free fp8 main: wave owns 64 rows (one speaker) x 512 cols.
// B-fragments read directly from L2 (Cb = 256 KB, L2-resident per XCD).
// No LDS, no __syncthreads. B pipelined as two 4-frag in-place groups.
__global__ __launch_bounds__(256, 2) void main_kernel(
    const float* __restrict__ embeds, const long* __restrict__ Cb,
    const float* __restrict__ normsum, const float* __restrict__ wp,
    const float* __restrict__ bp, float* __restrict__ ssumG,
    unsigned int* __restrict__ packG, float* __restrict__ gtlG) {
  int t = threadIdx.x;
  int wave = t >> 6, lane = t & 63;
  int c = lane & 15, q = lane >> 4;
  int b = blockIdx.x;               // 0..511
  int rg = b >> 1;                  // row group 0..255 (256 rows each)
  int h = b & 1;                    // column half: cols [h*512, h*512+512)
  int r0 = rg * 256 + wave * 64;    // global row base (one speaker)
  int jspk = r0 >> 6;               // this wave's speaker (diag column)

  float w = *wp, bia = *bp;
  const float L2E = 1.4426950408889634f;
  float M0 = fabsf(w) + bia;        // >= any logit (cosines in [-1,1])
  float wl = w * L2E;               // p = 2^(d*wl + cl) = exp(l - M0)
  float cl = (bia - M0) * L2E;
  float ns = normsum[jspk];

  int fb = h * 32 * 512 + lane;     // u64 fragment index base for this half

  // ---- issue tile-0 B loads early (overlap with A-phase) ----
  long bfA[4], bfB[4];
#pragma unroll
  for (int s = 0; s < 4; ++s) bfA[s] = Cb[fb + s * 64];
#pragma unroll
  for (int s = 0; s < 4; ++s) bfB[s] = Cb[fb + (4 + s) * 64];

  // ---- A fragments (64 rows x 256 K per wave, fp8) + row norms ----
  // A-frag layout: lane holds A[m = lane&15][k = q*8 + j(byte)], per (mt, s)
  long af[4][8];
  float n2p[4];
#pragma unroll
  for (int mt = 0; mt < 4; ++mt) {
    const float* rowp = embeds + (size_t)(r0 + mt * 16 + c) * NE;
    float acc2 = 0.f;
#pragma unroll
    for (int s = 0; s < 8; ++s) {
      int k0 = s * 32 + q * 8;
      float4 x = *(const float4*)(rowp + k0);
      float4 y = *(const float4*)(rowp + k0 + 4);
      acc2 += x.x * x.x + x.y * x.y + x.z * x.z + x.w * x.w;
      acc2 += y.x * y.x + y.y * y.y + y.z * y.z + y.w * y.w;
      unsigned int lo = pk4_fp8(x.x, x.y, x.z, x.w);
      unsigned int hi = pk4_fp8(y.x, y.y, y.z, y.w);
      af[mt][s] = (long)(((unsigned long long)hi << 32) | lo);
    }
    n2p[mt] = acc2;
  }
#pragma unroll
  for (int mt = 0; mt < 4; ++mt) {
    n2p[mt] += __shfl_xor(n2p[mt], 16, 64);  // reduce across q-groups
    n2p[mt] += __shfl_xor(n2p[mt], 32, 64);
  }
  // n2 of the rows THIS lane's C-registers cover (rows q*4+r), via shuffle
  float n2d[4][4];
#pragma unroll
  for (int mt = 0; mt < 4; ++mt)
#pragma unroll
    for (int r = 0; r < 4; ++r)
      n2d[mt][r] = __shfl(n2p[mt], q * 4 + r, 64);

  // ---- per-lane softmax state (4 mtiles x 4 regs = 16 row-slots) ----
  float ssum[4][4];
  unsigned int pm[4][4];
#pragma unroll
  for (int mt = 0; mt < 4; ++mt)
#pragma unroll
    for (int r = 0; r < 4; ++r) {
      ssum[mt][r] = 0.f;
      pm[mt][r] = 0u;
    }

  // ---- barrier-free loop over this half's 32 column tiles ----
#pragma unroll 1
  for (int T = 0; T < 32; ++T) {
    f32x4 acc[4];
#pragma unroll
    for (int mt = 0; mt < 4; ++mt) acc[mt] = (f32x4){0.f, 0.f, 0.f, 0.f};
    int nb = fb + (T + 1) * 512;
    bool more = (T + 1 < 32);
    // first half of K with group A, then refill group A for tile T+1
#pragma unroll
    for (int s = 0; s < 4; ++s)
#pragma unroll
      for (int mt = 0; mt < 4; ++mt)
        acc[mt] = __builtin_amdgcn_mfma_f32_16x16x32_fp8_fp8(
            af[mt][s], bfA[s], acc[mt], 0, 0, 0);
    if (more) {
#pragma unroll
      for (int s = 0; s < 4; ++s) bfA[s] = Cb[nb + s * 64];
    }
    // second half of K with group B, then refill group B for tile T+1
#pragma unroll
    for (int s = 0; s < 4; ++s)
#pragma unroll
      for (int mt = 0; mt < 4; ++mt)
        acc[mt] = __builtin_amdgcn_mfma_f32_16x16x32_fp8_fp8(
            af[mt][4 + s], bfB[s], acc[mt], 0, 0, 0);
    if (more) {
#pragma unroll
      for (int s = 0; s < 4; ++s) bfB[s] = Cb[nb + (4 + s) * 64];
    }

    int gt = h * 32 + T;
    int col = gt * 16 + c;
    bool diagstep = ((jspk >> 4) == gt);  // wave-uniform
#pragma unroll
    for (int mt = 0; mt < 4; ++mt) {
      f32x4 a = acc[mt];
      if (diagstep && c == (jspk & 15)) {
#pragma unroll
        for (int r = 0; r < 4; ++r) {
          float d = a[r];
          float n2 = n2d[mt][r];
          float Sv = d * ns;
          float den = fmaxf(fmaf(ns, ns, n2) - 2.f * Sv, 1e-30f);
          float val = (Sv - n2) * __frsqrt_rn(den);
          gtlG[r0 + mt * 16 + q * 4 + r] = fmaf(w, val, bia);
          a[r] = val;
        }
      }
#pragma unroll
      for (int r = 0; r < 4; ++r) {
        float p = exp2f(fmaf(a[r], wl, cl));  // exp(l - M0), monotone in l
        ssum[mt][r] += p;
        // pack p (top 22 bits) with 1023-col: argmax with low-col ties
        unsigned int pk =
            (__float_as_uint(p) & 0xfffffc00u) | (unsigned)(1023 - col);
        pm[mt][r] = pm[mt][r] > pk ? pm[mt][r] : pk;
      }
    }
  }

  // ---- cross-lane (16 column-lanes) reduce, then global atomic combine ----
#pragma unroll
  for (int mt = 0; mt < 4; ++mt)
#pragma unroll
    for (int r = 0; r < 4; ++r) {
      float s = ssum[mt][r];
      s += __shfl_xor(s, 1, 64);
      s += __shfl_xor(s, 2, 64);
      s += __shfl_xor(s, 4, 64);
      s += __shfl_xor(s, 8, 64);
      unsigned int m = pm[mt][r];
#pragma unroll
      for (int off = 1; off < 16; off <<= 1) {
        unsigned int m2 = __shfl_xor((int)m, off, 64);
        m = m > m2 ? m : m2;
      }
      if (c == 0) {
        int row = r0 + mt * 16 + q * 4 + r;
        atomicAdd(&ssumG[row], s);
        atomicMax(&packG[row], m);
      }
    }
}

__global__ __launch_bounds__(256) void reduce_kernel(
    const float* __restrict__ ssumG, const unsigned int* __restrict__ packG,
    const float* __restrict__ gtlG, const float* __restrict__ wp,
    const float* __restrict__ bp, float* __restrict__ out) {
  int i = blockIdx.x * 256 + threadIdx.x;  // row 0..65535
  int spk = i >> 6;
  float w = *wp, bia = *bp;
  float M0 = fabsf(w) + bia;
  float lossr = M0 + __logf(ssumG[i]) - gtlG[i];
  int amax = 1023 - (int)(packG[i] & 1023u);
  float corr = (amax == spk) ? 1.f : 0.f;
#pragma unroll
  for (int off = 32; off; off >>= 1) {
    lossr += __shfl_xor(lossr, off, 64);
    corr += __shfl_xor(corr, off, 64);
  }
  __shared__ float pl[4], pc[4];
  int wave = threadIdx.x >> 6, lane = threadIdx.x & 63;
  if (lane == 0) { pl[wave] = lossr; pc[wave] = corr; }
  __syncthreads();
  if (threadIdx.x == 0) {
    const float inv = 1.f / (float)(NS * NU);
    atomicAdd(&out[0], (pl[0] + pl[1] + pl[2] + pl[3]) * inv);
    atomicAdd(&out[1], (pc[0] + pc[1] + pc[2] + pc[3]) * inv);
  }
}

extern "C" void kernel_launch(void* const* d_in, const int* in_sizes, int n_in,
                              void* d_out, int out_size, void* d_ws,
                              size_t ws_size, hipStream_t stream) {
  const float* embeds = (const float*)d_in[0];
  const float* w = (const float*)d_in[1];
  const float* b = (const float*)d_in[2];
  float* out = (float*)d_out;
  char* ws = (char*)d_ws;
  unsigned int* Cb = (unsigned int*)ws;                     // 256 KB fp8
  unsigned int* packG = (unsigned int*)(ws + (256 << 10));  // 256 KB
  float* ssumG = (float*)(ws + (512 << 10));                // 256 KB
  float* gtlG = (float*)(ws + (768 << 10));                 // 256 KB
  float* normsum = (float*)(ws + (1024 << 10));             // 4 KB

  centroid_kernel<<<NS, 256, 0, stream>>>(embeds, Cb, normsum, ssumG, packG,
                                          out);
  main_kernel<<<512, 256, 0, stream>>>(embeds, (const long*)Cb, normsum, w, b,
                                       ssumG, packG, gtlG);
  reduce_kernel<<<NS * NU / 256, 256, 0, stream>>>(ssumG, packG, gtlG, w, b,
                                                   out);
}